// Round 3
// baseline (873.969 us; speedup 1.0000x reference)
//
#include <hip/hip_runtime.h>
#include <hip/hip_cooperative_groups.h>
#include <math.h>

namespace cg = cooperative_groups;

#define BN_EPS 1e-5f
#define NEG_SLOPE 0.2f

__device__ __forceinline__ float relu_f(float x) { return x > 0.f ? x : 0.f; }
__device__ __forceinline__ float leaky_f(float z) { return z > 0.f ? z : NEG_SLOPE * z; }

// ---- generic 32x64 GEMM tile, 256 threads, 2x4 micro. SELF: rows>=1024 = relu(Ahi+abias)
template <int K, int N, bool SELF>
__device__ void gemm_tile(const float* A, const float* Ahi, const float* abias,
                          const float* B, float* C, int m0, int n0,
                          float (*As)[33], float (*Bs)[64])
{
    int t = threadIdx.x;
    int tx = t & 15, ty = t >> 4;          // micro: rows ty*2+{0,1}, cols tx*4..
    int am = t >> 3, ak2 = (t & 7) * 2;    // A-stage: row am, k-offsets ak2,ak2+1
    bool hi = SELF && m0 >= 1024;
    const float* Ab = hi ? Ahi : A;
    float acc[2][4] = {};
    for (int k0 = 0; k0 < K; k0 += 16) {
        float2 av = *(const float2*)&Ab[(size_t)(m0 + am) * K + k0 + ak2];
        if (hi) {
            av.x = relu_f(av.x + abias[k0 + ak2]);
            av.y = relu_f(av.y + abias[k0 + ak2 + 1]);
        }
        float4 bv = *(const float4*)&B[(size_t)(k0 + ty) * N + n0 + tx * 4];
        __syncthreads();
        As[ak2][am] = av.x;
        As[ak2 + 1][am] = av.y;
        *(float4*)&Bs[ty][tx * 4] = bv;
        __syncthreads();
#pragma unroll
        for (int kk = 0; kk < 16; ++kk) {
            float a0 = As[kk][ty * 2], a1 = As[kk][ty * 2 + 1];
            float4 b4 = *(const float4*)&Bs[kk][tx * 4];
            acc[0][0] += a0 * b4.x; acc[0][1] += a0 * b4.y;
            acc[0][2] += a0 * b4.z; acc[0][3] += a0 * b4.w;
            acc[1][0] += a1 * b4.x; acc[1][1] += a1 * b4.y;
            acc[1][2] += a1 * b4.z; acc[1][3] += a1 * b4.w;
        }
    }
#pragma unroll
    for (int i = 0; i < 2; ++i) {
        float4 o = {acc[i][0], acc[i][1], acc[i][2], acc[i][3]};
        *(float4*)&C[(size_t)(m0 + ty * 2 + i) * N + n0 + tx * 4] = o;
    }
}

// ---- GAT aggregation split-K tile: C[v,c]=sum_u exp(leaky(s[u]+d[v])-m[v])*h[u,c]
template <int D, int KS>
__device__ void agg_tile(const float* h, const float* s, const float* d,
                         float* pacc, float* pden, int m0, int n0, int kz,
                         float* Ss, float (*As)[33], float (*Bs)[64],
                         float* red, float (*part)[32])
{
    int t = threadIdx.x;
    // stage s[0..1023] + grid-wide max (4 floats/thread)
    float4 sa = *(const float4*)&s[t * 4];
    *(float4*)&Ss[t * 4] = sa;
    float lm = fmaxf(fmaxf(sa.x, sa.y), fmaxf(sa.z, sa.w));
#pragma unroll
    for (int off = 1; off < 64; off <<= 1) lm = fmaxf(lm, __shfl_xor(lm, off));
    if ((t & 63) == 0) red[t >> 6] = lm;
    __syncthreads();
    float smax = fmaxf(fmaxf(red[0], red[1]), fmaxf(red[2], red[3]));

    int tx = t & 15, ty = t >> 4;
    int vg2 = tx * 2;                      // A-gen: u-row=ty, v-cols vg2,vg2+1
    float dv0 = d[m0 + vg2], dv1 = d[m0 + vg2 + 1];
    float mv0 = leaky_f(smax + dv0), mv1 = leaky_f(smax + dv1);
    float ds0 = 0.f, ds1 = 0.f;
    float acc[2][4] = {};
    const int CH = 1024 / KS;
    for (int k0 = kz * CH; k0 < kz * CH + CH; k0 += 16) {
        float4 bv = *(const float4*)&h[(size_t)(k0 + ty) * D + n0 + tx * 4];
        float su = Ss[k0 + ty];
        float a0 = __expf(leaky_f(su + dv0) - mv0);
        float a1 = __expf(leaky_f(su + dv1) - mv1);
        ds0 += a0; ds1 += a1;
        __syncthreads();
        As[ty][vg2] = a0;
        As[ty][vg2 + 1] = a1;
        *(float4*)&Bs[ty][tx * 4] = bv;
        __syncthreads();
#pragma unroll
        for (int kk = 0; kk < 16; ++kk) {
            float a0m = As[kk][ty * 2], a1m = As[kk][ty * 2 + 1];
            float4 b4 = *(const float4*)&Bs[kk][tx * 4];
            acc[0][0] += a0m * b4.x; acc[0][1] += a0m * b4.y;
            acc[0][2] += a0m * b4.z; acc[0][3] += a0m * b4.w;
            acc[1][0] += a1m * b4.x; acc[1][1] += a1m * b4.y;
            acc[1][2] += a1m * b4.z; acc[1][3] += a1m * b4.w;
        }
    }
    __syncthreads();
    part[ty][vg2] = ds0;
    part[ty][vg2 + 1] = ds1;
    __syncthreads();
#pragma unroll
    for (int i = 0; i < 2; ++i) {
        float4 o = {acc[i][0], acc[i][1], acc[i][2], acc[i][3]};
        *(float4*)&pacc[((size_t)kz * 1024 + m0 + ty * 2 + i) * D + n0 + tx * 4] = o;
    }
    if (t < 32) {
        float den = 0.f;
#pragma unroll
        for (int u = 0; u < 16; ++u) den += part[u][t];
        pden[kz * 1024 + m0 + t] = den;    // duplicated across n-tiles: same value, benign
    }
}

__global__ __launch_bounds__(256, 4) void fused_all(
    const float* __restrict__ img, const float* __restrict__ c1w, const float* __restrict__ c1b,
    const float* __restrict__ bn1g, const float* __restrict__ bn1b,
    const float* __restrict__ bn1m, const float* __restrict__ bn1v,
    const float* __restrict__ c2w, const float* __restrict__ c2b,
    const float* __restrict__ bn2g, const float* __restrict__ bn2b,
    const float* __restrict__ bn2m, const float* __restrict__ bn2v,
    const float* __restrict__ g1w, const float* __restrict__ g1as,
    const float* __restrict__ g1ad, const float* __restrict__ g1b,
    const float* __restrict__ g2w, const float* __restrict__ g2as,
    const float* __restrict__ g2ad, const float* __restrict__ g2b,
    const float* __restrict__ ow, const float* __restrict__ ob,
    float* ws, float* __restrict__ out)
{
    __shared__ float Ss[1024];
    __shared__ float As[16][33];
    __shared__ float Bs[16][64];
    __shared__ float red[4];
    __shared__ float part[16][32];

    const int r = blockIdx.x;
    const int t = threadIdx.x;
    const int G = gridDim.x;
    cg::grid_group grid = cg::this_grid();

    // ws layout (floats) — phase-ordered aliasing, all separated by grid.sync():
    float* x1    = ws;                   // 2,097,152 ; also conv2 planes (dead till combine1)
    float* bufc1 = ws + 2097152;         //   524,288
    float* h1    = ws + 2621440;         // 2,097,152 ; also pacc2 (dead after gemm2)
    float* x0    = ws + 4718592;         // 1,048,576 ; with h2 = pacc1 span; also x2
    float* h2    = ws + 5767168;         // 1,048,576
    float* s1    = ws + 6815744;
    float* d1    = ws + 6816768;
    float* s2    = ws + 6817792;
    float* d2    = ws + 6818816;
    float* pden1 = bufc1 + 16384;
    float* pden2 = bufc1 + 24576;
    float* pacc1 = x0;                   // 8*1024*256 floats (x0+h2 contiguous)
    float* pacc2 = h1;                   // 16*1024*128 floats
    float* x2    = x0;
    float* c2p   = x1;                   // 2 planes x 1,048,576

    // ---------------- phase 0: conv1+bn+relu+maxpool -> bufc1 [b][64][32][32] ----------------
    for (int vb = r; vb < 512; vb += G) {
        int q = vb & 3, cog = (vb >> 2) & 15, b = vb >> 6;
        int x = t & 31, y = (q << 3) + (t >> 5);
        float acc[4][4] = {};
#pragma unroll
        for (int ci = 0; ci < 3; ++ci) {
            const float* ib = img + (b * 3 + ci) * 4096;
            float rv[4][4];
#pragma unroll
            for (int rr = 0; rr < 4; ++rr) {
                int yy = 2 * y - 1 + rr;
                bool yok = (unsigned)yy < 64u;
                const float* p = ib + yy * 64 + 2 * x;
                float2 c01 = yok ? *(const float2*)p : make_float2(0.f, 0.f);
                rv[rr][1] = c01.x;
                rv[rr][2] = c01.y;
                rv[rr][0] = (yok && x > 0) ? p[-1] : 0.f;
                rv[rr][3] = (yok && x < 31) ? p[2] : 0.f;
            }
#pragma unroll
            for (int j = 0; j < 4; ++j) {
                const float* wj = c1w + ((cog * 4 + j) * 3 + ci) * 9;
#pragma unroll
                for (int ky = 0; ky < 3; ++ky)
#pragma unroll
                    for (int kx = 0; kx < 3; ++kx) {
                        float wvv = wj[ky * 3 + kx];
#pragma unroll
                        for (int py = 0; py < 2; ++py)
#pragma unroll
                            for (int px = 0; px < 2; ++px)
                                acc[j][py * 2 + px] += rv[py + ky][px + kx] * wvv;
                    }
            }
        }
#pragma unroll
        for (int j = 0; j < 4; ++j) {
            int co = cog * 4 + j;
            float inv = bn1g[co] / sqrtf(bn1v[co] + BN_EPS);
            float sh = c1b[co] * inv + (bn1b[co] - bn1m[co] * inv);
            float v0 = relu_f(acc[j][0] * inv + sh);
            float v1 = relu_f(acc[j][1] * inv + sh);
            float v2 = relu_f(acc[j][2] * inv + sh);
            float v3 = relu_f(acc[j][3] * inv + sh);
            bufc1[((b * 64 + co) * 32 + y) * 32 + x] = fmaxf(fmaxf(v0, v1), fmaxf(v2, v3));
        }
    }
    grid.sync();

    // ---------------- phase 1: conv2 split-K(2) -> block-linear planes in c2p ----------------
    for (int vb = r; vb < 1024; vb += G) {
        int kz = vb & 1, half = (vb >> 1) & 1, cog = (vb >> 2) & 31, b = vb >> 7;
        int x2p = (t & 15) * 2;
        int y = half * 16 + (t >> 4);
        bool xnz = x2p != 0;
        bool xhi = x2p == 30;
        const float* ibase = bufc1 + b * 65536 + kz * 32768;
        int xb = xnz ? x2p - 1 : 0;
        float acc[4][2] = {};
#pragma unroll 2
        for (int ci = 0; ci < 32; ++ci) {
            const float* cbp = ibase + ci * 1024;
            float rc[3][4];
#pragma unroll
            for (int rr = 0; rr < 3; ++rr) {
                int yy = y - 1 + rr;
                bool yok = (unsigned)yy < 32u;
                const float* p = cbp + yy * 32 + xb;
                float4 f = yok ? *(const float4*)p : make_float4(0.f, 0.f, 0.f, 0.f);
                rc[rr][0] = xnz ? f.x : 0.f;
                rc[rr][1] = xnz ? f.y : f.x;
                rc[rr][2] = xnz ? f.z : f.y;
                float r3 = xnz ? f.w : f.z;
                rc[rr][3] = xhi ? 0.f : r3;
            }
#pragma unroll
            for (int j = 0; j < 4; ++j) {
                const float* wj = c2w + ((cog * 4 + j) * 64 + kz * 32 + ci) * 9;
#pragma unroll
                for (int ky = 0; ky < 3; ++ky)
#pragma unroll
                    for (int kx = 0; kx < 3; ++kx) {
                        float wvv = wj[ky * 3 + kx];
                        acc[j][0] += rc[ky][kx] * wvv;
                        acc[j][1] += rc[ky][kx + 1] * wvv;
                    }
            }
        }
        float* pp = c2p + (size_t)kz * 1048576;
        int bid = b * 64 + cog * 2 + half;
        size_t base = ((size_t)bid * 256 + t) * 8;
        float4 s0 = {acc[0][0], acc[1][0], acc[2][0], acc[3][0]};
        float4 s1v = {acc[0][1], acc[1][1], acc[2][1], acc[3][1]};
        *(float4*)&pp[base] = s0;
        *(float4*)&pp[base + 4] = s1v;
    }
    grid.sync();

    // ---------------- phase 2: combine 2 planes + bias+BN+ReLU -> x0 [n][128] ----------------
    for (int vb = r; vb < 512; vb += G) {
        int bid = vb;
        int half = bid & 1, cog = (bid >> 1) & 31, b = bid >> 6;
        size_t off = ((size_t)bid * 256 + t) * 8;
        float4 u0 = *(const float4*)&c2p[off];
        float4 u1 = *(const float4*)&c2p[off + 4];
        float4 w0 = *(const float4*)&c2p[1048576 + off];
        float4 w1 = *(const float4*)&c2p[1048576 + off + 4];
        float sx = u0.x + w0.x, sy = u0.y + w0.y, sz = u0.z + w0.z, sw = u0.w + w0.w;
        float qx = u1.x + w1.x, qy = u1.y + w1.y, qz = u1.z + w1.z, qw = u1.w + w1.w;

        float4 gg = ((const float4*)bn2g)[cog];
        float4 vvv = ((const float4*)bn2v)[cog];
        float4 bbb = ((const float4*)bn2b)[cog];
        float4 mm = ((const float4*)bn2m)[cog];
        float4 cbb = ((const float4*)c2b)[cog];
        float ix = gg.x / sqrtf(vvv.x + BN_EPS);
        float iy = gg.y / sqrtf(vvv.y + BN_EPS);
        float iz = gg.z / sqrtf(vvv.z + BN_EPS);
        float iw = gg.w / sqrtf(vvv.w + BN_EPS);
        float shx = cbb.x * ix + (bbb.x - mm.x * ix);
        float shy = cbb.y * iy + (bbb.y - mm.y * iy);
        float shz = cbb.z * iz + (bbb.z - mm.z * iz);
        float shw = cbb.w * iw + (bbb.w - mm.w * iw);

        float4 o0 = {relu_f(sx * ix + shx), relu_f(sy * iy + shy),
                     relu_f(sz * iz + shz), relu_f(sw * iw + shw)};
        float4 o1 = {relu_f(qx * ix + shx), relu_f(qy * iy + shy),
                     relu_f(qz * iz + shz), relu_f(qw * iw + shw)};
        int y = half * 16 + (t >> 4), x2p = (t & 15) * 2;
        int n0 = b * 1024 + y * 32 + x2p;
        *(float4*)&x0[(size_t)n0 * 128 + cog * 4] = o0;
        *(float4*)&x0[(size_t)(n0 + 1) * 128 + cog * 4] = o1;
    }
    grid.sync();

    // ---------------- phase 3: gemm1 x0[8192x128] @ g1w[128x256] -> h1 ----------------
    for (int vb = r; vb < 1024; vb += G)
        gemm_tile<128, 256, false>(x0, x0, nullptr, g1w, h1, (vb >> 2) * 32, (vb & 3) * 64, As, Bs);
    grid.sync();

    // ---------------- phase 4: score1 (rows<1024) ----------------
    for (int wv = r * 4 + (t >> 6); wv < 1024; wv += G * 4) {
        int lane = t & 63;
        const float* hp = h1 + (size_t)wv * 256;
        float ss = 0.f, dd = 0.f;
#pragma unroll
        for (int c0 = 0; c0 < 256; c0 += 64) {
            float hv = hp[c0 + lane];
            ss += hv * g1as[c0 + lane];
            dd += hv * g1ad[c0 + lane];
        }
        for (int off = 32; off; off >>= 1) {
            ss += __shfl_down(ss, off);
            dd += __shfl_down(dd, off);
        }
        if (lane == 0) { s1[wv] = ss; d1[wv] = dd; }
    }
    grid.sync();

    // ---------------- phase 5: agg1 split-K(8) -> pacc1/pden1 ----------------
    for (int vb = r; vb < 1024; vb += G)
        agg_tile<256, 8>(h1, s1, d1, pacc1, pden1,
                         (vb >> 5) * 32, ((vb >> 3) & 3) * 64, vb & 7,
                         Ss, As, Bs, red, part);
    grid.sync();

    // ---------------- phase 6: combine1 -> x1 (rows<1024) ----------------
    for (int vb = r; vb < 256; vb += G) {
        int idx = (vb << 8) + t;
        int c4 = idx & 63, v = idx >> 6;
        float4 a = {0.f, 0.f, 0.f, 0.f};
        float den = 0.f;
#pragma unroll
        for (int ks = 0; ks < 8; ++ks) {
            float4 p = ((const float4*)pacc1)[(size_t)(ks * 1024 + v) * 64 + c4];
            a.x += p.x; a.y += p.y; a.z += p.z; a.w += p.w;
            den += pden1[ks * 1024 + v];
        }
        float rd = 1.f / den;
        float4 bz = ((const float4*)g1b)[c4];
        float4 o = {relu_f(a.x * rd + bz.x), relu_f(a.y * rd + bz.y),
                    relu_f(a.z * rd + bz.z), relu_f(a.w * rd + bz.w)};
        ((float4*)x1)[(size_t)v * 64 + c4] = o;
    }
    grid.sync();

    // ---------------- phase 7: gemm2 (rows<1024: x1; rows>=1024: relu(h1+g1b)) -> h2 ----------------
    for (int vb = r; vb < 512; vb += G)
        gemm_tile<256, 128, true>(x1, h1, g1b, g2w, h2, (vb >> 1) * 32, (vb & 1) * 64, As, Bs);
    grid.sync();

    // ---------------- phase 8: score2 ----------------
    for (int wv = r * 4 + (t >> 6); wv < 1024; wv += G * 4) {
        int lane = t & 63;
        const float* hp = h2 + (size_t)wv * 128;
        float ss = 0.f, dd = 0.f;
#pragma unroll
        for (int c0 = 0; c0 < 128; c0 += 64) {
            float hv = hp[c0 + lane];
            ss += hv * g2as[c0 + lane];
            dd += hv * g2ad[c0 + lane];
        }
        for (int off = 32; off; off >>= 1) {
            ss += __shfl_down(ss, off);
            dd += __shfl_down(dd, off);
        }
        if (lane == 0) { s2[wv] = ss; d2[wv] = dd; }
    }
    grid.sync();

    // ---------------- phase 9: agg2 split-K(16) -> pacc2/pden2 ----------------
    for (int vb = r; vb < 1024; vb += G)
        agg_tile<128, 16>(h2, s2, d2, pacc2, pden2,
                          (vb >> 5) * 32, ((vb >> 4) & 1) * 64, vb & 15,
                          Ss, As, Bs, red, part);
    grid.sync();

    // ---------------- phase 10: combine2 -> x2 (rows<1024) ----------------
    for (int vb = r; vb < 128; vb += G) {
        int idx = (vb << 8) + t;
        int c4 = idx & 31, v = idx >> 5;
        float4 a = {0.f, 0.f, 0.f, 0.f};
        float den = 0.f;
#pragma unroll
        for (int ks = 0; ks < 16; ++ks) {
            float4 p = ((const float4*)pacc2)[(size_t)(ks * 1024 + v) * 32 + c4];
            a.x += p.x; a.y += p.y; a.z += p.z; a.w += p.w;
            den += pden2[ks * 1024 + v];
        }
        float rd = 1.f / den;
        float4 bz = ((const float4*)g2b)[c4];
        float4 o = {relu_f(a.x * rd + bz.x), relu_f(a.y * rd + bz.y),
                    relu_f(a.z * rd + bz.z), relu_f(a.w * rd + bz.w)};
        ((float4*)x2)[(size_t)v * 32 + c4] = o;
    }
    grid.sync();

    // ---------------- phase 11: mean-pool + self-transform + head + log_softmax ----------------
    for (int vb = r; vb < 8; vb += G) {
        int b = vb;
        float* red256 = Ss;
        float* pooled = Ss + 256;
        float* logits = Ss + 384;
        int c = t & 127, hseg = t >> 7;
        float a0 = 0.f, a1 = 0.f, a2 = 0.f, a3 = 0.f;
        if (b == 0) {
            const float* p = x2 + ((size_t)hseg * 512) * 128 + c;
#pragma unroll 2
            for (int n = 0; n < 512; n += 4) {
                a0 += p[(size_t)n * 128];
                a1 += p[(size_t)(n + 1) * 128];
                a2 += p[(size_t)(n + 2) * 128];
                a3 += p[(size_t)(n + 3) * 128];
            }
        } else {
            float bz = g2b[c];
            const float* p = h2 + ((size_t)b * 1024 + hseg * 512) * 128 + c;
#pragma unroll 2
            for (int n = 0; n < 512; n += 4) {
                a0 += relu_f(p[(size_t)n * 128] + bz);
                a1 += relu_f(p[(size_t)(n + 1) * 128] + bz);
                a2 += relu_f(p[(size_t)(n + 2) * 128] + bz);
                a3 += relu_f(p[(size_t)(n + 3) * 128] + bz);
            }
        }
        red256[t] = (a0 + a1) + (a2 + a3);
        __syncthreads();
        if (t < 128) pooled[t] = (red256[t] + red256[t + 128]) * (1.f / 1024.f);
        __syncthreads();
        if (t < 10) {
            float l = ob[t];
            for (int cc = 0; cc < 128; ++cc) l += pooled[cc] * ow[cc * 10 + t];
            logits[t] = l;
        }
        __syncthreads();
        if (t == 0) {
            float mx = logits[0];
            for (int j = 1; j < 10; ++j) mx = fmaxf(mx, logits[j]);
            float sum = 0.f;
            for (int j = 0; j < 10; ++j) sum += expf(logits[j] - mx);
            float lse = mx + logf(sum);
            for (int j = 0; j < 10; ++j) out[b * 10 + j] = logits[j] - lse;
        }
        __syncthreads();
    }
}

extern "C" void kernel_launch(void* const* d_in, const int* in_sizes, int n_in,
                              void* d_out, int out_size, void* d_ws, size_t ws_size,
                              hipStream_t stream)
{
    const float* images = (const float*)d_in[0];
    const float* c1w = (const float*)d_in[1];
    const float* c1b = (const float*)d_in[2];
    const float* bn1g = (const float*)d_in[3];
    const float* bn1b = (const float*)d_in[4];
    const float* bn1m = (const float*)d_in[5];
    const float* bn1v = (const float*)d_in[6];
    const float* c2w = (const float*)d_in[7];
    const float* c2b = (const float*)d_in[8];
    const float* bn2g = (const float*)d_in[9];
    const float* bn2b = (const float*)d_in[10];
    const float* bn2m = (const float*)d_in[11];
    const float* bn2v = (const float*)d_in[12];
    const float* g1w = (const float*)d_in[13];
    const float* g1as = (const float*)d_in[14];
    const float* g1ad = (const float*)d_in[15];
    const float* g1b = (const float*)d_in[16];
    const float* g2w = (const float*)d_in[17];
    const float* g2as = (const float*)d_in[18];
    const float* g2ad = (const float*)d_in[19];
    const float* g2b = (const float*)d_in[20];
    const float* ow = (const float*)d_in[21];
    const float* ob = (const float*)d_in[22];
    float* out = (float*)d_out;
    float* wsf = (float*)d_ws;

    static int nblk = 0;
    if (nblk == 0) {
        int per_cu = 0;
        hipOccupancyMaxActiveBlocksPerMultiprocessor(&per_cu, fused_all, 256, 0);
        hipDeviceProp_t prop;
        int dev = 0;
        hipGetDevice(&dev);
        hipGetDeviceProperties(&prop, dev);
        if (per_cu < 1) per_cu = 1;
        long cap = (long)per_cu * prop.multiProcessorCount;
        nblk = cap < 1024 ? (int)cap : 1024;
    }

    void* params[25];
    params[0] = &images; params[1] = &c1w;  params[2] = &c1b;
    params[3] = &bn1g;   params[4] = &bn1b; params[5] = &bn1m;  params[6] = &bn1v;
    params[7] = &c2w;    params[8] = &c2b;
    params[9] = &bn2g;   params[10] = &bn2b; params[11] = &bn2m; params[12] = &bn2v;
    params[13] = &g1w;   params[14] = &g1as; params[15] = &g1ad; params[16] = &g1b;
    params[17] = &g2w;   params[18] = &g2as; params[19] = &g2ad; params[20] = &g2b;
    params[21] = &ow;    params[22] = &ob;   params[23] = &wsf;  params[24] = &out;

    hipLaunchCooperativeKernel((void*)fused_all, dim3(nblk), dim3(256), params, 0, stream);
}

// Round 4
// 204.312 us; speedup vs baseline: 4.2776x; 4.2776x over previous
//
#include <hip/hip_runtime.h>
#include <math.h>

#define BN_EPS 1e-5f
#define NEG_SLOPE 0.2f

__device__ __forceinline__ float relu_f(float x) { return x > 0.f ? x : 0.f; }
__device__ __forceinline__ float leaky_f(float z) { return z > 0.f ? z : NEG_SLOPE * z; }

// ---------------- conv1 (3->64, 3x3 SAME) fused bias+BN+ReLU+2x2maxpool ----------------
// grid 512 = b(8) x cog(16) x q(4); 256 threads = one pooled position, 4 co
__global__ void conv1_pool(const float* __restrict__ img, const float* __restrict__ w,
                           const float* __restrict__ cb, const float* __restrict__ g,
                           const float* __restrict__ bb, const float* __restrict__ m,
                           const float* __restrict__ vv, float* __restrict__ out)
{
    int blk = blockIdx.x;
    int q = blk & 3, cog = (blk >> 2) & 15, b = blk >> 6;
    int t = threadIdx.x;
    int x = t & 31, y = (q << 3) + (t >> 5);

    float acc[4][4] = {};
#pragma unroll
    for (int ci = 0; ci < 3; ++ci) {
        const float* ib = img + (b * 3 + ci) * 4096;
        float rv[4][4];
#pragma unroll
        for (int r = 0; r < 4; ++r) {
            int yy = 2 * y - 1 + r;
            bool yok = (unsigned)yy < 64u;
            const float* p = ib + yy * 64 + 2 * x;
            float2 c01 = yok ? *(const float2*)p : make_float2(0.f, 0.f);
            rv[r][1] = c01.x;
            rv[r][2] = c01.y;
            rv[r][0] = (yok && x > 0) ? p[-1] : 0.f;
            rv[r][3] = (yok && x < 31) ? p[2] : 0.f;
        }
#pragma unroll
        for (int j = 0; j < 4; ++j) {
            const float* wj = w + ((cog * 4 + j) * 3 + ci) * 9;
#pragma unroll
            for (int ky = 0; ky < 3; ++ky)
#pragma unroll
                for (int kx = 0; kx < 3; ++kx) {
                    float wvv = wj[ky * 3 + kx];
#pragma unroll
                    for (int py = 0; py < 2; ++py)
#pragma unroll
                        for (int px = 0; px < 2; ++px)
                            acc[j][py * 2 + px] += rv[py + ky][px + kx] * wvv;
                }
        }
    }
#pragma unroll
    for (int j = 0; j < 4; ++j) {
        int co = cog * 4 + j;
        float inv = g[co] / sqrtf(vv[co] + BN_EPS);
        float sh = cb[co] * inv + (bb[co] - m[co] * inv);
        float v0 = relu_f(acc[j][0] * inv + sh);
        float v1 = relu_f(acc[j][1] * inv + sh);
        float v2 = relu_f(acc[j][2] * inv + sh);
        float v3 = relu_f(acc[j][3] * inv + sh);
        out[((b * 64 + co) * 32 + y) * 32 + x] = fmaxf(fmaxf(v0, v1), fmaxf(v2, v3));
    }
}

// ---------------- conv2: 64->128, 3x3 SAME, SPLIT-K over ci (4 ways) ----------------
// grid 2048 = b(8) x cog(32) x half(2) x kz(4); kz in LOW bits.
// Partials stored BLOCK-LINEAR (fully coalesced): plane[kz] at ((bid*256+t)*8),
// bid = b*64+cog*2+half. The scatter to [n][128] happens once, in combine, on 4MB only.
__global__ void conv2_split(const float* __restrict__ in, const float* __restrict__ w,
                            float* __restrict__ pacc01, float* __restrict__ pacc23)
{
    int blk = blockIdx.x;
    int kz = blk & 3, half = (blk >> 2) & 1, cog = (blk >> 3) & 31, b = blk >> 8;
    int t = threadIdx.x;
    int x2p = (t & 15) * 2;
    int y = half * 16 + (t >> 4);
    bool xnz = x2p != 0;
    bool xhi = x2p == 30;
    const float* ibase = in + b * 64 * 1024 + kz * 16 * 1024;
    int xb = xnz ? x2p - 1 : 0;

    float acc[4][2] = {};

#pragma unroll 2
    for (int ci = 0; ci < 16; ++ci) {
        const float* cb2 = ibase + ci * 1024;
        float rc[3][4];
#pragma unroll
        for (int r = 0; r < 3; ++r) {
            int yy = y - 1 + r;
            bool yok = (unsigned)yy < 32u;
            const float* p = cb2 + yy * 32 + xb;
            float4 f = yok ? *(const float4*)p : make_float4(0.f, 0.f, 0.f, 0.f);
            rc[r][0] = xnz ? f.x : 0.f;
            rc[r][1] = xnz ? f.y : f.x;
            rc[r][2] = xnz ? f.z : f.y;
            float r3 = xnz ? f.w : f.z;
            rc[r][3] = xhi ? 0.f : r3;
        }
#pragma unroll
        for (int j = 0; j < 4; ++j) {
            const float* wj = w + ((cog * 4 + j) * 64 + kz * 16 + ci) * 9;
#pragma unroll
            for (int ky = 0; ky < 3; ++ky)
#pragma unroll
                for (int kx = 0; kx < 3; ++kx) {
                    float wvv = wj[ky * 3 + kx];
                    acc[j][0] += rc[ky][kx] * wvv;
                    acc[j][1] += rc[ky][kx + 1] * wvv;
                }
        }
    }

    float* pp = (kz & 2 ? pacc23 : pacc01) + (size_t)(kz & 1) * 1048576;
    int bid = b * 64 + cog * 2 + half;
    size_t base = ((size_t)bid * 256 + t) * 8;
    float4 s0 = {acc[0][0], acc[1][0], acc[2][0], acc[3][0]};
    float4 s1 = {acc[0][1], acc[1][1], acc[2][1], acc[3][1]};
    *(float4*)&pp[base] = s0;
    *(float4*)&pp[base + 4] = s1;
}

// combine 4 kz planes (block-linear layout) + bias + BN + ReLU -> x0 [n][128]
// grid 512 x 256; reads fully coalesced, scattered 16B writes only on the 4MB output
__global__ void conv2_combine(const float* __restrict__ p01, const float* __restrict__ p23,
                              const float* __restrict__ cb, const float* __restrict__ g,
                              const float* __restrict__ bb, const float* __restrict__ m,
                              const float* __restrict__ vv, float* __restrict__ x0)
{
    int gid = blockIdx.x * 256 + threadIdx.x;   // [0, 131072)
    int t = gid & 255, bid = gid >> 8;
    int half = bid & 1, cog = (bid >> 1) & 31, b = bid >> 6;
    size_t off = (size_t)gid * 8;

    float4 s0 = {0.f, 0.f, 0.f, 0.f}, s1 = {0.f, 0.f, 0.f, 0.f};
    const float* pl0 = p01;
    const float* pl1 = p01 + 1048576;
    const float* pl2 = p23;
    const float* pl3 = p23 + 1048576;
#pragma unroll
    for (int kz = 0; kz < 4; ++kz) {
        const float* pp = kz == 0 ? pl0 : kz == 1 ? pl1 : kz == 2 ? pl2 : pl3;
        float4 u0 = *(const float4*)&pp[off];
        float4 u1 = *(const float4*)&pp[off + 4];
        s0.x += u0.x; s0.y += u0.y; s0.z += u0.z; s0.w += u0.w;
        s1.x += u1.x; s1.y += u1.y; s1.z += u1.z; s1.w += u1.w;
    }

    float4 gg = ((const float4*)g)[cog];
    float4 vvv = ((const float4*)vv)[cog];
    float4 bbb = ((const float4*)bb)[cog];
    float4 mm = ((const float4*)m)[cog];
    float4 cbb = ((const float4*)cb)[cog];
    float ix = gg.x / sqrtf(vvv.x + BN_EPS);
    float iy = gg.y / sqrtf(vvv.y + BN_EPS);
    float iz = gg.z / sqrtf(vvv.z + BN_EPS);
    float iw = gg.w / sqrtf(vvv.w + BN_EPS);
    float shx = cbb.x * ix + (bbb.x - mm.x * ix);
    float shy = cbb.y * iy + (bbb.y - mm.y * iy);
    float shz = cbb.z * iz + (bbb.z - mm.z * iz);
    float shw = cbb.w * iw + (bbb.w - mm.w * iw);

    float4 o0 = {relu_f(s0.x * ix + shx), relu_f(s0.y * iy + shy),
                 relu_f(s0.z * iz + shz), relu_f(s0.w * iw + shw)};
    float4 o1 = {relu_f(s1.x * ix + shx), relu_f(s1.y * iy + shy),
                 relu_f(s1.z * iz + shz), relu_f(s1.w * iw + shw)};

    int y = half * 16 + (t >> 4), x2p = (t & 15) * 2;
    int n0 = b * 1024 + y * 32 + x2p;
    *(float4*)&x0[(size_t)n0 * 128 + cog * 4] = o0;
    *(float4*)&x0[(size_t)(n0 + 1) * 128 + cog * 4] = o1;
}

// ---------------- tiled GEMM: 32x64 tile, 128 threads, 4x4 micro ----------------
// grid (M/32, N/64).
// SELF: rows >= 1024 read Ahi and apply relu(a + abias) on load (fused self-loop path).
// SCORE: blocks with m0<1024 also emit per-n-tile partial attention scores:
//   sp[by*1024 + row] = sum_{c in this 64-col slice} C[row,c]*asrc[c]   (dp likewise)
template <int K, int N, bool SELF, bool SCORE>
__global__ void gemm32(const float* __restrict__ A, const float* __restrict__ Ahi,
                       const float* __restrict__ abias,
                       const float* __restrict__ B, float* __restrict__ C,
                       const float* __restrict__ asrc, const float* __restrict__ adst,
                       float* __restrict__ sp, float* __restrict__ dp)
{
    __shared__ float As[16][32];
    __shared__ float Bs[16][64];
    int t = threadIdx.x;
    int m0 = blockIdx.x * 32;
    int n0 = blockIdx.y * 64;
    int tx = t & 15, ty = t >> 4;          // micro: rows ty*4.., cols tx*4..
    int am = t >> 2, akq = (t & 3) * 4;    // A-stage
    bool hi = SELF && m0 >= 1024;
    const float* Ab = hi ? Ahi : A;
    float acc[4][4] = {};

    for (int k0 = 0; k0 < K; k0 += 16) {
        float4 av = *(const float4*)&Ab[(size_t)(m0 + am) * K + k0 + akq];
        if (hi) {
            float4 bz = *(const float4*)&abias[k0 + akq];
            av.x = relu_f(av.x + bz.x);
            av.y = relu_f(av.y + bz.y);
            av.z = relu_f(av.z + bz.z);
            av.w = relu_f(av.w + bz.w);
        }
        float4 bv0 = *(const float4*)&B[(size_t)(k0 + ty) * N + n0 + tx * 4];
        float4 bv1 = *(const float4*)&B[(size_t)(k0 + 8 + ty) * N + n0 + tx * 4];
        __syncthreads();
        As[akq + 0][am] = av.x;
        As[akq + 1][am] = av.y;
        As[akq + 2][am] = av.z;
        As[akq + 3][am] = av.w;
        *(float4*)&Bs[ty][tx * 4] = bv0;
        *(float4*)&Bs[ty + 8][tx * 4] = bv1;
        __syncthreads();
#pragma unroll
        for (int kk = 0; kk < 16; ++kk) {
            float4 a4 = *(const float4*)&As[kk][ty * 4];
            float4 b4 = *(const float4*)&Bs[kk][tx * 4];
            float aa[4] = {a4.x, a4.y, a4.z, a4.w};
            float bb4[4] = {b4.x, b4.y, b4.z, b4.w};
#pragma unroll
            for (int i = 0; i < 4; ++i)
#pragma unroll
                for (int j = 0; j < 4; ++j)
                    acc[i][j] += aa[i] * bb4[j];
        }
    }
#pragma unroll
    for (int i = 0; i < 4; ++i) {
        float4 o = {acc[i][0], acc[i][1], acc[i][2], acc[i][3]};
        *(float4*)&C[(size_t)(m0 + ty * 4 + i) * N + n0 + tx * 4] = o;
    }

    if (SCORE && m0 < 1024) {
        float4 as4 = *(const float4*)&asrc[n0 + tx * 4];
        float4 ad4 = *(const float4*)&adst[n0 + tx * 4];
#pragma unroll
        for (int i = 0; i < 4; ++i) {
            float ss = acc[i][0] * as4.x + acc[i][1] * as4.y +
                       acc[i][2] * as4.z + acc[i][3] * as4.w;
            float dd = acc[i][0] * ad4.x + acc[i][1] * ad4.y +
                       acc[i][2] * ad4.z + acc[i][3] * ad4.w;
#pragma unroll
            for (int off = 1; off < 16; off <<= 1) {
                ss += __shfl_xor(ss, off);
                dd += __shfl_xor(dd, off);
            }
            if (tx == 0) {
                sp[blockIdx.y * 1024 + m0 + ty * 4 + i] = ss;
                dp[blockIdx.y * 1024 + m0 + ty * 4 + i] = dd;
            }
        }
    }
}

// ---------------- GAT aggregation as split-K GEMM, 32x64 tile, 128 threads ----------------
// C[v,c] = sum_u exp(leaky(s[u]+d[v]) - m[v]) * h[u,c];  m[v] = leaky(smax + d[v])
// s/d come as NT per-n-tile partials (sp[nt*1024+u]); summed at staging (deterministic).
// grid (32, D/64, KS); 128 threads
template <int D, int KS, int NT>
__global__ void gat_agg_gemm(const float* __restrict__ h, const float* __restrict__ sp,
                             const float* __restrict__ dp, float* __restrict__ pacc,
                             float* __restrict__ pden)
{
    __shared__ float Ss[1024];
    __shared__ float As[16][32];
    __shared__ float Bs[16][64];
    __shared__ float red[2];
    __shared__ float part[16][32];

    const int CH = 1024 / KS;
    int t = threadIdx.x;
    int m0 = blockIdx.x * 32;
    int n0 = blockIdx.y * 64;
    int kz = blockIdx.z;
    int tx = t & 15, ty = t >> 4;
    int ug = t >> 3, vg4 = (t & 7) * 4;   // A-gen: u-row ug, v-cols vg4..+3

    // stage s (8 per thread, summing NT partials) + global max
    float4 sa = {0.f, 0.f, 0.f, 0.f}, sb = {0.f, 0.f, 0.f, 0.f};
#pragma unroll
    for (int nt = 0; nt < NT; ++nt) {
        float4 u = *(const float4*)&sp[nt * 1024 + t * 8];
        float4 v = *(const float4*)&sp[nt * 1024 + t * 8 + 4];
        sa.x += u.x; sa.y += u.y; sa.z += u.z; sa.w += u.w;
        sb.x += v.x; sb.y += v.y; sb.z += v.z; sb.w += v.w;
    }
    *(float4*)&Ss[t * 8] = sa;
    *(float4*)&Ss[t * 8 + 4] = sb;
    float lm = fmaxf(fmaxf(fmaxf(sa.x, sa.y), fmaxf(sa.z, sa.w)),
                     fmaxf(fmaxf(sb.x, sb.y), fmaxf(sb.z, sb.w)));
#pragma unroll
    for (int off = 1; off < 64; off <<= 1) lm = fmaxf(lm, __shfl_xor(lm, off));
    if ((t & 63) == 0) red[t >> 6] = lm;
    __syncthreads();
    float smax = fmaxf(red[0], red[1]);

    float4 dv = {0.f, 0.f, 0.f, 0.f};
#pragma unroll
    for (int nt = 0; nt < NT; ++nt) {
        float4 u = *(const float4*)&dp[nt * 1024 + m0 + vg4];
        dv.x += u.x; dv.y += u.y; dv.z += u.z; dv.w += u.w;
    }
    float4 mv = {leaky_f(smax + dv.x), leaky_f(smax + dv.y),
                 leaky_f(smax + dv.z), leaky_f(smax + dv.w)};
    float4 dsum = {0.f, 0.f, 0.f, 0.f};
    float acc[4][4] = {};

    for (int k0 = kz * CH; k0 < kz * CH + CH; k0 += 16) {
        float4 bv0 = *(const float4*)&h[(size_t)(k0 + ty) * D + n0 + tx * 4];
        float4 bv1 = *(const float4*)&h[(size_t)(k0 + 8 + ty) * D + n0 + tx * 4];
        float su = Ss[k0 + ug];
        float4 avv;
        avv.x = __expf(leaky_f(su + dv.x) - mv.x);
        avv.y = __expf(leaky_f(su + dv.y) - mv.y);
        avv.z = __expf(leaky_f(su + dv.z) - mv.z);
        avv.w = __expf(leaky_f(su + dv.w) - mv.w);
        dsum.x += avv.x; dsum.y += avv.y; dsum.z += avv.z; dsum.w += avv.w;
        __syncthreads();
        *(float4*)&As[ug][vg4] = avv;
        *(float4*)&Bs[ty][tx * 4] = bv0;
        *(float4*)&Bs[ty + 8][tx * 4] = bv1;
        __syncthreads();
#pragma unroll
        for (int kk = 0; kk < 16; ++kk) {
            float4 a4 = *(const float4*)&As[kk][ty * 4];
            float4 b4 = *(const float4*)&Bs[kk][tx * 4];
            float aa[4] = {a4.x, a4.y, a4.z, a4.w};
            float bb4[4] = {b4.x, b4.y, b4.z, b4.w};
#pragma unroll
            for (int i = 0; i < 4; ++i)
#pragma unroll
                for (int j = 0; j < 4; ++j)
                    acc[i][j] += aa[i] * bb4[j];
        }
    }

    __syncthreads();
    *(float4*)&part[ug][vg4] = dsum;
    __syncthreads();

#pragma unroll
    for (int i = 0; i < 4; ++i) {
        int r = ty * 4 + i;
        float4 o = {acc[i][0], acc[i][1], acc[i][2], acc[i][3]};
        *(float4*)&pacc[((size_t)kz * 1024 + m0 + r) * D + n0 + tx * 4] = o;
    }
    if (t < 32) {
        float den = 0.f;
#pragma unroll
        for (int u = 0; u < 16; ++u) den += part[u][t];
        pden[kz * 1024 + m0 + t] = den;   // redundant across n0-blocks: same value, benign
    }
}

// combine split-K partials: out[v,c] = relu(sum_ks pacc / sum_ks pden + bias), v < 1024
template <int D, int KS>
__global__ void gat_combine(const float* __restrict__ pacc, const float* __restrict__ pden,
                            const float* __restrict__ bias, float* __restrict__ out)
{
    int idx = blockIdx.x * blockDim.x + threadIdx.x;
    if (idx >= 1024 * D / 4) return;
    int c4 = idx & (D / 4 - 1);
    int v = idx / (D / 4);
    float4 a = {0.f, 0.f, 0.f, 0.f};
    float den = 0.f;
#pragma unroll
    for (int ks = 0; ks < KS; ++ks) {
        float4 p = ((const float4*)pacc)[(size_t)(ks * 1024 + v) * (D / 4) + c4];
        a.x += p.x; a.y += p.y; a.z += p.z; a.w += p.w;
        den += pden[ks * 1024 + v];
    }
    float rd = 1.f / den;
    float4 bz = ((const float4*)bias)[c4];
    float4 o = {relu_f(a.x * rd + bz.x), relu_f(a.y * rd + bz.y),
                relu_f(a.z * rd + bz.z), relu_f(a.w * rd + bz.w)};
    ((float4*)out)[(size_t)v * (D / 4) + c4] = o;
}

// ---------------- mean-pool stage 1 (fused self-transform): 128 blocks, each sums 64 rows ----
// image 0 reads x2 (already relu'd); images 1..7 read relu(h2 + g2b) on the fly
__global__ void pool_part(const float* __restrict__ x2, const float* __restrict__ h2,
                          const float* __restrict__ bias2, float* __restrict__ part)
{
    int b = blockIdx.x >> 4, seg = blockIdx.x & 15, t = threadIdx.x;
    float acc = 0.f;
    if (b == 0) {
        const float* p = x2 + ((size_t)seg * 64) * 128 + t;
#pragma unroll 8
        for (int n = 0; n < 64; ++n) acc += p[(size_t)n * 128];
    } else {
        float bz = bias2[t];
        const float* p = h2 + ((size_t)b * 1024 + seg * 64) * 128 + t;
#pragma unroll 8
        for (int n = 0; n < 64; ++n) acc += relu_f(p[(size_t)n * 128] + bz);
    }
    part[(b * 16 + seg) * 128 + t] = acc;
}

// ---------------- head: reduce partials + linear + log_softmax ----------------
__global__ void head_kernel(const float* __restrict__ part, const float* __restrict__ ow,
                            const float* __restrict__ ob, float* __restrict__ out)
{
    __shared__ float pooled[128];
    __shared__ float logits[10];
    int b = blockIdx.x, t = threadIdx.x;
    float acc = 0.f;
#pragma unroll
    for (int sgi = 0; sgi < 16; ++sgi) acc += part[(b * 16 + sgi) * 128 + t];
    pooled[t] = acc * (1.f / 1024.f);
    __syncthreads();
    if (t < 10) {
        float l = ob[t];
        for (int c = 0; c < 128; ++c) l += pooled[c] * ow[c * 10 + t];
        logits[t] = l;
    }
    __syncthreads();
    if (t == 0) {
        float mx = logits[0];
        for (int j = 1; j < 10; ++j) mx = fmaxf(mx, logits[j]);
        float sum = 0.f;
        for (int j = 0; j < 10; ++j) sum += expf(logits[j] - mx);
        float lse = mx + logf(sum);
        for (int j = 0; j < 10; ++j) out[b * 10 + j] = logits[j] - lse;
    }
}

extern "C" void kernel_launch(void* const* d_in, const int* in_sizes, int n_in,
                              void* d_out, int out_size, void* d_ws, size_t ws_size,
                              hipStream_t stream)
{
    const float* images = (const float*)d_in[0];
    const float* c1w = (const float*)d_in[1];
    const float* c1b = (const float*)d_in[2];
    const float* bn1g = (const float*)d_in[3];
    const float* bn1b = (const float*)d_in[4];
    const float* bn1m = (const float*)d_in[5];
    const float* bn1v = (const float*)d_in[6];
    const float* c2w = (const float*)d_in[7];
    const float* c2b = (const float*)d_in[8];
    const float* bn2g = (const float*)d_in[9];
    const float* bn2b = (const float*)d_in[10];
    const float* bn2m = (const float*)d_in[11];
    const float* bn2v = (const float*)d_in[12];
    const float* g1w = (const float*)d_in[13];
    const float* g1as = (const float*)d_in[14];
    const float* g1ad = (const float*)d_in[15];
    const float* g1b = (const float*)d_in[16];
    const float* g2w = (const float*)d_in[17];
    const float* g2as = (const float*)d_in[18];
    const float* g2ad = (const float*)d_in[19];
    const float* g2b = (const float*)d_in[20];
    const float* ow = (const float*)d_in[21];
    const float* ob = (const float*)d_in[22];
    float* out = (float*)d_out;

    // ws layout (floats):
    // [x1 2,097,152][bufc1 524,288][h1 2,097,152][x0 1,048,576][h2 1,048,576][scores 12K]
    // conv2 planes 0/1 alias x1 (dead till combine1); planes 2/3 alias h1 (overwritten by
    // gemm1 after combine consumed them). pacc1 aliases x0+h2 (x0 dead after gemm1; h2
    // unwritten yet). pacc2 aliases h1 (dead after gemm2, its last reader). x2 = x0
    // (pacc1 low half, dead after combine1). part/pden alias bufc1 (dead after conv2_split).
    float* ws = (float*)d_ws;
    float* x1    = ws;                   // 2,097,152
    float* bufc1 = ws + 2097152;         //   524,288
    float* h1    = ws + 2621440;         // 2,097,152
    float* x0    = ws + 4718592;         // 1,048,576
    float* h2    = ws + 5767168;         // 1,048,576
    float* sp1   = ws + 6815744;         // 4 x 1024 partial src-scores (per n-tile)
    float* dp1   = ws + 6819840;         // 4 x 1024
    float* sp2   = ws + 6823936;         // 2 x 1024
    float* dp2   = ws + 6825984;         // 2 x 1024
    float* part  = bufc1;                // 16,384
    float* pden1 = bufc1 + 16384;        // 8,192
    float* pden2 = bufc1 + 24576;        // 16,384
    float* pacc1 = x0;                   // 8*1024*256 = 2,097,152 (spans x0+h2)
    float* pacc2 = h1;                   // 16*1024*128 = 2,097,152
    float* x2    = x0;
    float* c2p01 = x1;                   // conv2 split planes 0,1 (2*1,048,576)
    float* c2p23 = h1;                   // conv2 split planes 2,3 (2*1,048,576)

    conv1_pool<<<512, 256, 0, stream>>>(images, c1w, c1b, bn1g, bn1b, bn1m, bn1v, bufc1);
    conv2_split<<<2048, 256, 0, stream>>>(bufc1, c2w, c2p01, c2p23);
    conv2_combine<<<512, 256, 0, stream>>>(c2p01, c2p23, c2b, bn2g, bn2b, bn2m, bn2v, x0);

    // gemm1 + fused score1 partials (4 n-tiles)
    gemm32<128, 256, false, true><<<dim3(256, 4), 128, 0, stream>>>(
        x0, x0, nullptr, g1w, h1, g1as, g1ad, sp1, dp1);
    gat_agg_gemm<256, 8, 4><<<dim3(32, 4, 8), 128, 0, stream>>>(h1, sp1, dp1, pacc1, pden1);
    gat_combine<256, 8><<<256, 256, 0, stream>>>(pacc1, pden1, g1b, x1);

    // gemm2: rows<1024 from x1; rows>=1024 = relu(h1+g1b) fused; + fused score2 partials
    gemm32<256, 128, true, true><<<dim3(256, 2), 128, 0, stream>>>(
        x1, h1, g1b, g2w, h2, g2as, g2ad, sp2, dp2);
    gat_agg_gemm<128, 16, 2><<<dim3(32, 2, 16), 128, 0, stream>>>(h2, sp2, dp2, pacc2, pden2);
    gat_combine<128, 16><<<128, 256, 0, stream>>>(pacc2, pden2, g2b, x2);

    pool_part<<<128, 128, 0, stream>>>(x2, h2, g2b, part);
    head_kernel<<<8, 128, 0, stream>>>(part, ow, ob, out);
}